// Round 1
// baseline (186.175 us; speedup 1.0000x reference)
//
#include <hip/hip_runtime.h>
#include <hip/hip_bf16.h>

typedef __bf16 bf16x8 __attribute__((ext_vector_type(8)));
typedef float f32x4 __attribute__((ext_vector_type(4)));

#define MFMA16(a, b, c) __builtin_amdgcn_mfma_f32_16x16x32_bf16(a, b, c, 0, 0, 0)

// Problem constants (fixed by the reference)
static constexpr int S_ = 1024;     // sequence
static constexpr int D_ = 1024;     // model dim
static constexpr int H_ = 16;       // heads
static constexpr int M_ = 4096;     // B*S rows

__device__ __forceinline__ void gload_lds16(const void* g, void* l) {
  __builtin_amdgcn_global_load_lds((const __attribute__((address_space(1))) void*)g,
                                   (__attribute__((address_space(3))) void*)l, 16, 0, 0);
}

// ---------------- f32 -> bf16 elementwise convert (8 elems/thread) ----------------
__global__ __launch_bounds__(256) void cvt_bf16(const float* __restrict__ in,
                                                __bf16* __restrict__ out, int n8) {
  int i = blockIdx.x * 256 + threadIdx.x;
  if (i >= n8) return;
  const float4* p = (const float4*)in + (size_t)i * 2;
  float4 a = p[0], b = p[1];
  bf16x8 o;
  o[0] = (__bf16)a.x; o[1] = (__bf16)a.y; o[2] = (__bf16)a.z; o[3] = (__bf16)a.w;
  o[4] = (__bf16)b.x; o[5] = (__bf16)b.y; o[6] = (__bf16)b.z; o[7] = (__bf16)b.w;
  *((bf16x8*)out + i) = o;
}

// ---------------- per-head weight [H][D][64] -> transposed bf16 [H*64][D] ----------------
__global__ __launch_bounds__(256) void wtrans(const float* __restrict__ w,
                                              __bf16* __restrict__ out, float scale) {
  __shared__ float tile[64][65];
  const int h = blockIdx.x, d0 = blockIdx.y * 64;
  const int t = threadIdx.x;
  const int r = t >> 2, c0 = (t & 3) * 16;
  const float4* s4 = (const float4*)(w + ((size_t)h * 1024 + d0 + r) * 64 + c0);
#pragma unroll
  for (int j = 0; j < 4; ++j) {
    float4 v = s4[j];
    tile[r][c0 + 4 * j + 0] = v.x; tile[r][c0 + 4 * j + 1] = v.y;
    tile[r][c0 + 4 * j + 2] = v.z; tile[r][c0 + 4 * j + 3] = v.w;
  }
  __syncthreads();
  // out[(h*64 + dk)][d0 + kidx] = tile[kidx][dk] * scale ; dk = r, kidx = c0..c0+15
  __bf16* dst = out + ((size_t)(h * 64 + r)) * 1024 + d0 + c0;
  bf16x8 o0, o1;
#pragma unroll
  for (int j = 0; j < 8; ++j) o0[j] = (__bf16)(tile[c0 + j][r] * scale);
#pragma unroll
  for (int j = 0; j < 8; ++j) o1[j] = (__bf16)(tile[c0 + 8 + j][r] * scale);
  *(bf16x8*)dst = o0;
  *(bf16x8*)(dst + 8) = o1;
}

// ---------------- 128x128 bf16 GEMM, B stored [N][K] (m97 structure) ----------------
// MODE 0: write bf16 to per-head layout [B][H][S][64]
// MODE 1: write f32 = acc + resid (row-major [M][N])
template <int MODE>
__device__ __forceinline__ void gemm_core(const __bf16* __restrict__ A,
                                          const __bf16* __restrict__ Bt,
                                          __bf16* __restrict__ outb,
                                          float* __restrict__ outf,
                                          const float* __restrict__ resid) {
  __shared__ __bf16 As[128 * 32];
  __shared__ __bf16 Bs[128 * 32];
  const int bn = blockIdx.x, bm = blockIdx.y;
  const int tid = threadIdx.x, lane = tid & 63;
  const int w = tid >> 6;
  const int wr = (w >> 1) * 64, wc = (w & 1) * 64;
  const int lr = lane & 15, lh = lane >> 4;

  f32x4 acc[4][4];
#pragma unroll
  for (int m = 0; m < 4; ++m)
#pragma unroll
    for (int n = 0; n < 4; ++n) {
      f32x4 z = {0.f, 0.f, 0.f, 0.f};
      acc[m][n] = z;
    }

  for (int kt = 0; kt < 1024 / 32; ++kt) {
#pragma unroll
    for (int i = 0; i < 2; ++i) {
      int o = i * 4096 + tid * 16;  // byte offset in 8KB tile
      int row = o >> 6, cb = o & 63;
      gload_lds16((const char*)A + (((size_t)(bm * 128 + row)) * 1024 + kt * 32) * 2 + cb,
                  (char*)As + o);
      gload_lds16((const char*)Bt + (((size_t)(bn * 128 + row)) * 1024 + kt * 32) * 2 + cb,
                  (char*)Bs + o);
    }
    __syncthreads();
    bf16x8 af[4], bfr[4];
#pragma unroll
    for (int m = 0; m < 4; ++m) af[m] = *(const bf16x8*)&As[(wr + m * 16 + lr) * 32 + lh * 8];
#pragma unroll
    for (int n = 0; n < 4; ++n) bfr[n] = *(const bf16x8*)&Bs[(wc + n * 16 + lr) * 32 + lh * 8];
#pragma unroll
    for (int m = 0; m < 4; ++m)
#pragma unroll
      for (int n = 0; n < 4; ++n) acc[m][n] = MFMA16(af[m], bfr[n], acc[m][n]);
    __syncthreads();
  }

  const int r0 = bm * 128 + wr + lh * 4;
  const int c0 = bn * 128 + wc + lr;
#pragma unroll
  for (int m = 0; m < 4; ++m)
#pragma unroll
    for (int n = 0; n < 4; ++n)
#pragma unroll
      for (int reg = 0; reg < 4; ++reg) {
        int row = r0 + m * 16 + reg;
        int col = c0 + n * 16;
        float v = acc[m][n][reg];
        if (MODE == 0) {
          // [B][H][S][64]: b=row>>10, s=row&1023, h=col>>6, dk=col&63
          outb[((((size_t)(row >> 10)) * 16 + (col >> 6)) * 1024 + (row & 1023)) * 64 +
               (col & 63)] = (__bf16)v;
        } else {
          size_t idx = (size_t)row * 1024 + col;
          outf[idx] = v + resid[idx];
        }
      }
}

__global__ __launch_bounds__(256) void gemm_qkv(const __bf16* __restrict__ A,
                                                const __bf16* __restrict__ Bt,
                                                __bf16* __restrict__ O) {
  const int z = blockIdx.z;
  gemm_core<0>(A + (size_t)z * 4194304, Bt + (size_t)z * 1048576, O + (size_t)z * 4194304,
               nullptr, nullptr);
}

__global__ __launch_bounds__(256) void gemm_fc(const __bf16* __restrict__ A,
                                               const __bf16* __restrict__ Bt,
                                               float* __restrict__ O,
                                               const float* __restrict__ resid) {
  gemm_core<1>(A, Bt, nullptr, O, resid);
}

// ---------------- flash attention: grid (S/64, H, B), 256 threads ----------------
__global__ __launch_bounds__(256) void attn_kernel(const __bf16* __restrict__ HEADS,
                                                   const int* __restrict__ mask,
                                                   __bf16* __restrict__ concat) {
  const __bf16* QH = HEADS;
  const __bf16* KH = HEADS + (size_t)M_ * 1024;
  const __bf16* VH = HEADS + (size_t)2 * M_ * 1024;
  __shared__ __bf16 Ks[64 * 64];
  __shared__ __bf16 Vt[64 * 64];
  __shared__ __bf16 Ps[4][16 * 64];
  const int qt = blockIdx.x, h = blockIdx.y, b = blockIdx.z;
  const int tid = threadIdx.x, lane = tid & 63, w = tid >> 6;
  const int lr = lane & 15, lh = lane >> 4;
  const size_t headoff = ((size_t)b * 16 + h) * 1024 * 64;
  const __bf16* Qp = QH + headoff;
  const __bf16* Kp = KH + headoff;
  const __bf16* Vp = VH + headoff;

  bf16x8 qa[2];
  {
    const __bf16* qptr = Qp + ((size_t)(qt * 64 + w * 16 + lr)) * 64 + lh * 8;
    qa[0] = *(const bf16x8*)qptr;
    qa[1] = *(const bf16x8*)(qptr + 32);
  }
  f32x4 oacc[4];
#pragma unroll
  for (int g = 0; g < 4; ++g) {
    f32x4 z = {0.f, 0.f, 0.f, 0.f};
    oacc[g] = z;
  }
  float mrow[4], lrow[4];
#pragma unroll
  for (int r = 0; r < 4; ++r) { mrow[r] = -3.0e38f; lrow[r] = 0.f; }

  const int qg0 = qt * 64 + w * 16 + lh * 4;
  const int* mrowp = mask + ((size_t)b * 1024 + qg0) * 1024;

  for (int kt = 0; kt < 16; ++kt) {
    // stage K tile (contiguous 8KB)
#pragma unroll
    for (int i = 0; i < 2; ++i) {
      int o = i * 4096 + tid * 16;
      gload_lds16((const char*)Kp + (size_t)kt * 8192 + o, (char*)Ks + o);
    }
    // stage V transposed: Vt[dv][kk]
    {
      const int kk = tid >> 2, dv0 = (tid & 3) * 16;
      const __bf16* vsrc = Vp + ((size_t)kt * 64 + kk) * 64 + dv0;
      bf16x8 v0 = *(const bf16x8*)vsrc;
      bf16x8 v1 = *(const bf16x8*)(vsrc + 8);
#pragma unroll
      for (int j = 0; j < 8; ++j) Vt[(dv0 + j) * 64 + kk] = v0[j];
#pragma unroll
      for (int j = 0; j < 8; ++j) Vt[(dv0 + 8 + j) * 64 + kk] = v1[j];
    }
    __syncthreads();

    // S = Q K^T   (16 q-rows x 64 kk per wave)
    f32x4 s[4];
#pragma unroll
    for (int n = 0; n < 4; ++n) {
      f32x4 z = {0.f, 0.f, 0.f, 0.f};
      s[n] = z;
    }
#pragma unroll
    for (int n = 0; n < 4; ++n)
#pragma unroll
      for (int h2 = 0; h2 < 2; ++h2) {
        bf16x8 kb = *(const bf16x8*)&Ks[(n * 16 + lr) * 64 + h2 * 32 + lh * 8];
        s[n] = MFMA16(qa[h2], kb, s[n]);
      }

    // mask
    const int kk0 = kt * 64 + lr;
#pragma unroll
    for (int n = 0; n < 4; ++n)
#pragma unroll
      for (int r = 0; r < 4; ++r) {
        int mv = mrowp[(size_t)r * 1024 + kk0 + n * 16];
        s[n][r] = mv ? s[n][r] : -1.0e9f;
      }

    // online softmax (row spread over 16 lanes: lane&15 = kk)
    float pmax[4];
#pragma unroll
    for (int r = 0; r < 4; ++r)
      pmax[r] = fmaxf(fmaxf(s[0][r], s[1][r]), fmaxf(s[2][r], s[3][r]));
#pragma unroll
    for (int off = 1; off < 16; off <<= 1)
#pragma unroll
      for (int r = 0; r < 4; ++r) pmax[r] = fmaxf(pmax[r], __shfl_xor(pmax[r], off, 64));

    float al[4], rsum[4];
#pragma unroll
    for (int r = 0; r < 4; ++r) {
      float mnew = fmaxf(mrow[r], pmax[r]);
      al[r] = __expf(mrow[r] - mnew);
      mrow[r] = mnew;
      rsum[r] = 0.f;
    }
#pragma unroll
    for (int n = 0; n < 4; ++n)
#pragma unroll
      for (int r = 0; r < 4; ++r) {
        float p = __expf(s[n][r] - mrow[r]);
        s[n][r] = p;
        rsum[r] += p;
      }
#pragma unroll
    for (int off = 1; off < 16; off <<= 1)
#pragma unroll
      for (int r = 0; r < 4; ++r) rsum[r] += __shfl_xor(rsum[r], off, 64);
#pragma unroll
    for (int r = 0; r < 4; ++r) lrow[r] = lrow[r] * al[r] + rsum[r];
#pragma unroll
    for (int g = 0; g < 4; ++g)
#pragma unroll
      for (int r = 0; r < 4; ++r) oacc[g][r] *= al[r];

    // P -> LDS (redistribute to A-fragment layout), wave-local
#pragma unroll
    for (int n = 0; n < 4; ++n)
#pragma unroll
      for (int r = 0; r < 4; ++r)
        Ps[w][(lh * 4 + r) * 64 + n * 16 + lr] = (__bf16)s[n][r];
    bf16x8 pa[2];
#pragma unroll
    for (int h2 = 0; h2 < 2; ++h2)
      pa[h2] = *(const bf16x8*)&Ps[w][lr * 64 + h2 * 32 + lh * 8];

    // O += P V
#pragma unroll
    for (int g = 0; g < 4; ++g)
#pragma unroll
      for (int h2 = 0; h2 < 2; ++h2) {
        bf16x8 vb = *(const bf16x8*)&Vt[(g * 16 + lr) * 64 + h2 * 32 + lh * 8];
        oacc[g] = MFMA16(pa[h2], vb, oacc[g]);
      }
    __syncthreads();
  }

  // epilogue: concat[b*1024 + q][h*64 + dv]
#pragma unroll
  for (int r = 0; r < 4; ++r) {
    float inv = 1.0f / lrow[r];
#pragma unroll
    for (int g = 0; g < 4; ++g)
      concat[((size_t)b * 1024 + qg0 + r) * 1024 + h * 64 + g * 16 + lr] =
          (__bf16)(oacc[g][r] * inv);
  }
}

// ---------------- LayerNorm (row per block) ----------------
__global__ __launch_bounds__(256) void ln_kernel(const float* __restrict__ in,
                                                 const float* __restrict__ gam,
                                                 const float* __restrict__ bet,
                                                 float* __restrict__ out) {
  const int row = blockIdx.x, t = threadIdx.x;
  const float4* x4 = (const float4*)(in + (size_t)row * 1024);
  float4 v = x4[t];
  float s = v.x + v.y + v.z + v.w;
  float sq = v.x * v.x + v.y * v.y + v.z * v.z + v.w * v.w;
#pragma unroll
  for (int off = 1; off < 64; off <<= 1) {
    s += __shfl_xor(s, off, 64);
    sq += __shfl_xor(sq, off, 64);
  }
  __shared__ float red[8];
  const int w = t >> 6, lane = t & 63;
  if (lane == 0) { red[w] = s; red[4 + w] = sq; }
  __syncthreads();
  s = red[0] + red[1] + red[2] + red[3];
  sq = red[4] + red[5] + red[6] + red[7];
  const float mu = s * (1.0f / 1024.0f);
  const float var = sq * (1.0f / 1024.0f) - mu * mu;
  const float rstd = rsqrtf(var + 1e-6f);
  float4 g4 = ((const float4*)gam)[t];
  float4 b4 = ((const float4*)bet)[t];
  float4 o;
  o.x = (v.x - mu) * rstd * g4.x + b4.x;
  o.y = (v.y - mu) * rstd * g4.y + b4.y;
  o.z = (v.z - mu) * rstd * g4.z + b4.z;
  o.w = (v.w - mu) * rstd * g4.w + b4.w;
  ((float4*)(out + (size_t)row * 1024))[t] = o;
}

extern "C" void kernel_launch(void* const* d_in, const int* in_sizes, int n_in,
                              void* d_out, int out_size, void* d_ws, size_t ws_size,
                              hipStream_t stream) {
  (void)in_sizes; (void)n_in; (void)out_size; (void)ws_size;
  const float* q = (const float*)d_in[0];
  const float* k = (const float*)d_in[1];
  const float* v = (const float*)d_in[2];
  const int* mask = (const int*)d_in[3];
  const float* wq = (const float*)d_in[4];
  const float* wk = (const float*)d_in[5];
  const float* wv = (const float*)d_in[6];
  const float* fc_w = (const float*)d_in[7];
  const float* ln_g = (const float*)d_in[8];
  const float* ln_b = (const float*)d_in[9];
  float* out = (float*)d_out;

  // workspace layout (80 MB total)
  __bf16* QKVBF = (__bf16*)d_ws;                       // 3 * 4194304 bf16
  __bf16* W3T   = QKVBF + 3ull * 4194304;              // 3 * 1048576 bf16
  __bf16* WFC   = W3T + 3ull * 1048576;                // 1048576 bf16
  __bf16* HEADS = WFC + 1048576;                       // 3 * 4194304 bf16
  __bf16* CONCAT = HEADS + 3ull * 4194304;             // 4194304 bf16
  float* OUT1 = (float*)(CONCAT + 4194304);            // 4194304 f32

  cvt_bf16<<<2048, 256, 0, stream>>>(q, QKVBF, 524288);
  cvt_bf16<<<2048, 256, 0, stream>>>(k, QKVBF + 4194304, 524288);
  cvt_bf16<<<2048, 256, 0, stream>>>(v, QKVBF + 2ull * 4194304, 524288);
  cvt_bf16<<<512, 256, 0, stream>>>(fc_w, WFC, 131072);
  dim3 wt(16, 16);
  wtrans<<<wt, 256, 0, stream>>>(wq, W3T, 0.125f);                  // fold 1/sqrt(DK)
  wtrans<<<wt, 256, 0, stream>>>(wk, W3T + 1048576, 1.0f);
  wtrans<<<wt, 256, 0, stream>>>(wv, W3T + 2ull * 1048576, 1.0f);

  gemm_qkv<<<dim3(8, 32, 3), 256, 0, stream>>>(QKVBF, W3T, HEADS);
  attn_kernel<<<dim3(16, 16, 4), 256, 0, stream>>>(HEADS, mask, CONCAT);
  gemm_fc<<<dim3(8, 32), 256, 0, stream>>>(CONCAT, WFC, OUT1, q);
  ln_kernel<<<4096, 256, 0, stream>>>(OUT1, ln_g, ln_b, out);
}

// Round 2
// 153.493 us; speedup vs baseline: 1.2129x; 1.2129x over previous
//
#include <hip/hip_runtime.h>
#include <hip/hip_bf16.h>

typedef __bf16 bf16x8 __attribute__((ext_vector_type(8)));
typedef float f32x4 __attribute__((ext_vector_type(4)));

#define MFMA16(a, b, c) __builtin_amdgcn_mfma_f32_16x16x32_bf16(a, b, c, 0, 0, 0)

static constexpr int M_ = 4096;     // B*S rows

__device__ __forceinline__ void gload_lds16(const void* g, void* l) {
  __builtin_amdgcn_global_load_lds((const __attribute__((address_space(1))) void*)g,
                                   (__attribute__((address_space(3))) void*)l, 16, 0, 0);
}

// swizzled LDS u16 index for 64-col bf16 tiles: 8 granules of 16B per 128B row,
// stored granule = logical granule ^ (row & 7)
#define SWZ(rowv, c16) (((rowv) * 64) + (((c16) ^ ((rowv) & 7)) * 8))

// ---------------- f32 -> bf16 convert: q,k,v in one launch ----------------
__global__ __launch_bounds__(256) void cvt3(const float* __restrict__ q,
                                            const float* __restrict__ k,
                                            const float* __restrict__ v,
                                            __bf16* __restrict__ out) {
  const float* src = blockIdx.y == 0 ? q : (blockIdx.y == 1 ? k : v);
  __bf16* dst = out + (size_t)blockIdx.y * 4194304;
  int i = blockIdx.x * 256 + threadIdx.x;           // 2048 blocks * 256 = 524288
  const float4* p = (const float4*)src + (size_t)i * 2;
  float4 a = p[0], b = p[1];
  bf16x8 o;
  o[0] = (__bf16)a.x; o[1] = (__bf16)a.y; o[2] = (__bf16)a.z; o[3] = (__bf16)a.w;
  o[4] = (__bf16)b.x; o[5] = (__bf16)b.y; o[6] = (__bf16)b.z; o[7] = (__bf16)b.w;
  *((bf16x8*)dst + i) = o;
}

__global__ __launch_bounds__(256) void cvt_bf16(const float* __restrict__ in,
                                                __bf16* __restrict__ out, int n8) {
  int i = blockIdx.x * 256 + threadIdx.x;
  if (i >= n8) return;
  const float4* p = (const float4*)in + (size_t)i * 2;
  float4 a = p[0], b = p[1];
  bf16x8 o;
  o[0] = (__bf16)a.x; o[1] = (__bf16)a.y; o[2] = (__bf16)a.z; o[3] = (__bf16)a.w;
  o[4] = (__bf16)b.x; o[5] = (__bf16)b.y; o[6] = (__bf16)b.z; o[7] = (__bf16)b.w;
  *((bf16x8*)out + i) = o;
}

// ---------------- per-head weight [H][D][64] -> transposed bf16 [H*64][D], x3 ----------------
__global__ __launch_bounds__(256) void wtrans3(const float* __restrict__ wq,
                                               const float* __restrict__ wk,
                                               const float* __restrict__ wv,
                                               __bf16* __restrict__ out) {
  const int z = blockIdx.z;
  const float* w = z == 0 ? wq : (z == 1 ? wk : wv);
  const float scale = z == 0 ? 0.125f : 1.0f;       // fold 1/sqrt(DK) into W_q
  __bf16* o = out + (size_t)z * 1048576;
  __shared__ float tile[64][65];
  const int h = blockIdx.x, d0 = blockIdx.y * 64;
  const int t = threadIdx.x;
  const int r = t >> 2, c0 = (t & 3) * 16;
  const float4* s4 = (const float4*)(w + ((size_t)h * 1024 + d0 + r) * 64 + c0);
#pragma unroll
  for (int j = 0; j < 4; ++j) {
    float4 vv = s4[j];
    tile[r][c0 + 4 * j + 0] = vv.x; tile[r][c0 + 4 * j + 1] = vv.y;
    tile[r][c0 + 4 * j + 2] = vv.z; tile[r][c0 + 4 * j + 3] = vv.w;
  }
  __syncthreads();
  __bf16* dst = o + ((size_t)(h * 64 + r)) * 1024 + d0 + c0;
  bf16x8 o0, o1;
#pragma unroll
  for (int j = 0; j < 8; ++j) o0[j] = (__bf16)(tile[c0 + j][r] * scale);
#pragma unroll
  for (int j = 0; j < 8; ++j) o1[j] = (__bf16)(tile[c0 + 8 + j][r] * scale);
  *(bf16x8*)dst = o0;
  *(bf16x8*)(dst + 8) = o1;
}

// ---------------- V transpose: [B*H][1024][64] -> [B*H][64][1024] ----------------
__global__ __launch_bounds__(256) void vtrans(const __bf16* __restrict__ V,
                                              __bf16* __restrict__ VT) {
  __shared__ __bf16 t[64][65];
  const int bh = blockIdx.y;
  const int s0 = blockIdx.x * 64;
  const int tid = threadIdx.x;
  const int r = tid >> 2, c0 = (tid & 3) * 16;
  const __bf16* src = V + ((size_t)bh * 1024 + s0 + r) * 64 + c0;
  bf16x8 a = *(const bf16x8*)src;
  bf16x8 b = *(const bf16x8*)(src + 8);
#pragma unroll
  for (int j = 0; j < 8; ++j) { t[r][c0 + j] = a[j]; t[r][c0 + 8 + j] = b[j]; }
  __syncthreads();
  bf16x8 o0, o1;
#pragma unroll
  for (int j = 0; j < 8; ++j) o0[j] = t[c0 + j][r];
#pragma unroll
  for (int j = 0; j < 8; ++j) o1[j] = t[c0 + 8 + j][r];
  __bf16* dst = VT + ((size_t)bh * 64 + r) * 1024 + s0 + c0;
  *(bf16x8*)dst = o0;
  *(bf16x8*)(dst + 8) = o1;
}

// ---------------- 128x128 bf16 GEMM, B stored [N][K] (m97 structure) ----------------
template <int MODE>
__device__ __forceinline__ void gemm_core(const __bf16* __restrict__ A,
                                          const __bf16* __restrict__ Bt,
                                          __bf16* __restrict__ outb,
                                          float* __restrict__ outf,
                                          const float* __restrict__ resid) {
  __shared__ __bf16 As[128 * 32];
  __shared__ __bf16 Bs[128 * 32];
  const int bn = blockIdx.x, bm = blockIdx.y;
  const int tid = threadIdx.x, lane = tid & 63;
  const int w = tid >> 6;
  const int wr = (w >> 1) * 64, wc = (w & 1) * 64;
  const int lr = lane & 15, lh = lane >> 4;

  f32x4 acc[4][4];
#pragma unroll
  for (int m = 0; m < 4; ++m)
#pragma unroll
    for (int n = 0; n < 4; ++n) {
      f32x4 z = {0.f, 0.f, 0.f, 0.f};
      acc[m][n] = z;
    }

  for (int kt = 0; kt < 1024 / 32; ++kt) {
#pragma unroll
    for (int i = 0; i < 2; ++i) {
      int o = i * 4096 + tid * 16;
      int row = o >> 6, cb = o & 63;
      gload_lds16((const char*)A + (((size_t)(bm * 128 + row)) * 1024 + kt * 32) * 2 + cb,
                  (char*)As + o);
      gload_lds16((const char*)Bt + (((size_t)(bn * 128 + row)) * 1024 + kt * 32) * 2 + cb,
                  (char*)Bs + o);
    }
    __syncthreads();
    bf16x8 af[4], bfr[4];
#pragma unroll
    for (int m = 0; m < 4; ++m) af[m] = *(const bf16x8*)&As[(wr + m * 16 + lr) * 32 + lh * 8];
#pragma unroll
    for (int n = 0; n < 4; ++n) bfr[n] = *(const bf16x8*)&Bs[(wc + n * 16 + lr) * 32 + lh * 8];
#pragma unroll
    for (int m = 0; m < 4; ++m)
#pragma unroll
      for (int n = 0; n < 4; ++n) acc[m][n] = MFMA16(af[m], bfr[n], acc[m][n]);
    __syncthreads();
  }

  const int r0 = bm * 128 + wr + lh * 4;
  const int c0 = bn * 128 + wc + lr;
#pragma unroll
  for (int m = 0; m < 4; ++m)
#pragma unroll
    for (int n = 0; n < 4; ++n)
#pragma unroll
      for (int reg = 0; reg < 4; ++reg) {
        int row = r0 + m * 16 + reg;
        int col = c0 + n * 16;
        float v = acc[m][n][reg];
        if (MODE == 0) {
          outb[((((size_t)(row >> 10)) * 16 + (col >> 6)) * 1024 + (row & 1023)) * 64 +
               (col & 63)] = (__bf16)v;
        } else {
          size_t idx = (size_t)row * 1024 + col;
          outf[idx] = v + resid[idx];
        }
      }
}

__global__ __launch_bounds__(256) void gemm_qkv(const __bf16* __restrict__ A,
                                                const __bf16* __restrict__ Bt,
                                                __bf16* __restrict__ O) {
  const int z = blockIdx.z;
  gemm_core<0>(A + (size_t)z * 4194304, Bt + (size_t)z * 1048576, O + (size_t)z * 4194304,
               nullptr, nullptr);
}

__global__ __launch_bounds__(256) void gemm_fc(const __bf16* __restrict__ A,
                                               const __bf16* __restrict__ Bt,
                                               float* __restrict__ O,
                                               const float* __restrict__ resid) {
  gemm_core<1>(A, Bt, nullptr, O, resid);
}

// ---------------- flash attention: grid 1024 (XCD-remapped), 256 threads ----------------
__global__ __launch_bounds__(256) void attn_kernel(const __bf16* __restrict__ HEADS,
                                                   const __bf16* __restrict__ VT,
                                                   const int* __restrict__ mask,
                                                   __bf16* __restrict__ concat) {
  const __bf16* QH = HEADS;
  const __bf16* KH = HEADS + (size_t)M_ * 1024;
  __shared__ __bf16 Ks[2][64 * 64];
  __shared__ __bf16 Vs[2][64 * 64];
  __shared__ __bf16 Ps[4][16 * 64];

  // XCD-aware remap: each XCD gets whole (b,h) groups -> K/V tiles reuse in its L2
  const int d = blockIdx.x;                 // 0..1023
  const int xcd = d & 7, j = d >> 3;        // 128 work items per xcd
  const int grp = xcd * 8 + (j >> 4);       // 0..63 = (b,h) pair
  const int qt = j & 15;
  const int h = grp & 15, b = grp >> 4;

  const int tid = threadIdx.x, lane = tid & 63, w = tid >> 6;
  const int lr = lane & 15, lh = lane >> 4;
  const size_t headoff = ((size_t)b * 16 + h) * 65536;
  const char* Kbase = (const char*)(KH + headoff);
  const char* Vbase = (const char*)(VT + headoff);   // [64][1024] per head

  // staging coordinates: chunk i covers LDS bytes (i*256+tid)*16
  int koff[2], voff[2], ldso[2];
#pragma unroll
  for (int i = 0; i < 2; ++i) {
    int L = i * 256 + tid;
    int row = L >> 3, g = L & 7;
    int gsw = g ^ (row & 7);
    ldso[i] = L * 16;
    koff[i] = row * 128 + gsw * 16;        // K tile rows: 128B stride, contiguous tile
    voff[i] = row * 2048 + gsw * 16;       // V^T rows: 2048B global stride
  }

  bf16x8 qa[2];
  {
    const __bf16* qptr = QH + headoff + ((size_t)(qt * 64 + w * 16 + lr)) * 64 + lh * 8;
    qa[0] = *(const bf16x8*)qptr;
    qa[1] = *(const bf16x8*)(qptr + 32);
  }
  f32x4 oacc[4];
#pragma unroll
  for (int g = 0; g < 4; ++g) {
    f32x4 z = {0.f, 0.f, 0.f, 0.f};
    oacc[g] = z;
  }
  float mrow[4], lrow[4];
#pragma unroll
  for (int r = 0; r < 4; ++r) { mrow[r] = -3.0e38f; lrow[r] = 0.f; }

  const int qg0 = qt * 64 + w * 16 + lh * 4;
  const int* mrowp = mask + ((size_t)b * 1024 + qg0) * 1024 + lr;

  // prologue: stage tile 0
#pragma unroll
  for (int i = 0; i < 2; ++i) {
    gload_lds16(Kbase + koff[i], (char*)Ks[0] + ldso[i]);
    gload_lds16(Vbase + voff[i], (char*)Vs[0] + ldso[i]);
  }
  __syncthreads();

  for (int kt = 0; kt < 16; ++kt) {
    const int cur = kt & 1;
    // issue next-tile stage early (hides under compute; drained by end-of-iter barrier)
    if (kt < 15) {
#pragma unroll
      for (int i = 0; i < 2; ++i) {
        gload_lds16(Kbase + (size_t)(kt + 1) * 8192 + koff[i], (char*)Ks[cur ^ 1] + ldso[i]);
        gload_lds16(Vbase + (size_t)(kt + 1) * 128 + voff[i], (char*)Vs[cur ^ 1] + ldso[i]);
      }
    }
    // mask loads issued early: latency hides under QK^T
    int mv[4][4];
#pragma unroll
    for (int n = 0; n < 4; ++n)
#pragma unroll
      for (int r = 0; r < 4; ++r)
        mv[n][r] = mrowp[(size_t)r * 1024 + kt * 64 + n * 16];

    // S = Q K^T
    f32x4 s[4];
#pragma unroll
    for (int n = 0; n < 4; ++n) {
      f32x4 z = {0.f, 0.f, 0.f, 0.f};
      s[n] = z;
    }
    __builtin_amdgcn_s_setprio(1);
#pragma unroll
    for (int n = 0; n < 4; ++n)
#pragma unroll
      for (int h2 = 0; h2 < 2; ++h2) {
        bf16x8 kb = *(const bf16x8*)&Ks[cur][SWZ(n * 16 + lr, h2 * 4 + lh)];
        s[n] = MFMA16(qa[h2], kb, s[n]);
      }
    __builtin_amdgcn_s_setprio(0);

    // mask
#pragma unroll
    for (int n = 0; n < 4; ++n)
#pragma unroll
      for (int r = 0; r < 4; ++r) s[n][r] = mv[n][r] ? s[n][r] : -1.0e9f;

    // online softmax (row spread over 16 lanes)
    float pmax[4];
#pragma unroll
    for (int r = 0; r < 4; ++r)
      pmax[r] = fmaxf(fmaxf(s[0][r], s[1][r]), fmaxf(s[2][r], s[3][r]));
#pragma unroll
    for (int off = 1; off < 16; off <<= 1)
#pragma unroll
      for (int r = 0; r < 4; ++r) pmax[r] = fmaxf(pmax[r], __shfl_xor(pmax[r], off, 64));

    float al[4], rsum[4];
#pragma unroll
    for (int r = 0; r < 4; ++r) {
      float mnew = fmaxf(mrow[r], pmax[r]);
      al[r] = __expf(mrow[r] - mnew);
      mrow[r] = mnew;
      rsum[r] = 0.f;
    }
#pragma unroll
    for (int n = 0; n < 4; ++n)
#pragma unroll
      for (int r = 0; r < 4; ++r) {
        float p = __expf(s[n][r] - mrow[r]);
        s[n][r] = p;
        rsum[r] += p;
      }
#pragma unroll
    for (int off = 1; off < 16; off <<= 1)
#pragma unroll
      for (int r = 0; r < 4; ++r) rsum[r] += __shfl_xor(rsum[r], off, 64);
#pragma unroll
    for (int r = 0; r < 4; ++r) lrow[r] = lrow[r] * al[r] + rsum[r];
#pragma unroll
    for (int g = 0; g < 4; ++g)
#pragma unroll
      for (int r = 0; r < 4; ++r) oacc[g][r] *= al[r];

    // P -> LDS (swizzled), wave-local
#pragma unroll
    for (int n = 0; n < 4; ++n)
#pragma unroll
      for (int r = 0; r < 4; ++r) {
        int prow = lh * 4 + r;
        int gl = n * 2 + (lr >> 3);
        Ps[w][prow * 64 + ((gl ^ (prow & 7)) * 8) + (lr & 7)] = (__bf16)s[n][r];
      }
    bf16x8 pa[2];
#pragma unroll
    for (int h2 = 0; h2 < 2; ++h2)
      pa[h2] = *(const bf16x8*)&Ps[w][SWZ(lr, h2 * 4 + lh)];

    // O += P V
    __builtin_amdgcn_s_setprio(1);
#pragma unroll
    for (int g = 0; g < 4; ++g)
#pragma unroll
      for (int h2 = 0; h2 < 2; ++h2) {
        bf16x8 vb = *(const bf16x8*)&Vs[cur][SWZ(g * 16 + lr, h2 * 4 + lh)];
        oacc[g] = MFMA16(pa[h2], vb, oacc[g]);
      }
    __builtin_amdgcn_s_setprio(0);
    __syncthreads();   // drains next-tile stage (vmcnt) + protects Ks/Vs reuse
  }

  // epilogue
#pragma unroll
  for (int r = 0; r < 4; ++r) {
    float inv = 1.0f / lrow[r];
#pragma unroll
    for (int g = 0; g < 4; ++g)
      concat[((size_t)b * 1024 + qg0 + r) * 1024 + h * 64 + g * 16 + lr] =
          (__bf16)(oacc[g][r] * inv);
  }
}

// ---------------- LayerNorm ----------------
__global__ __launch_bounds__(256) void ln_kernel(const float* __restrict__ in,
                                                 const float* __restrict__ gam,
                                                 const float* __restrict__ bet,
                                                 float* __restrict__ out) {
  const int row = blockIdx.x, t = threadIdx.x;
  const float4* x4 = (const float4*)(in + (size_t)row * 1024);
  float4 v = x4[t];
  float s = v.x + v.y + v.z + v.w;
  float sq = v.x * v.x + v.y * v.y + v.z * v.z + v.w * v.w;
#pragma unroll
  for (int off = 1; off < 64; off <<= 1) {
    s += __shfl_xor(s, off, 64);
    sq += __shfl_xor(sq, off, 64);
  }
  __shared__ float red[8];
  const int w = t >> 6, lane = t & 63;
  if (lane == 0) { red[w] = s; red[4 + w] = sq; }
  __syncthreads();
  s = red[0] + red[1] + red[2] + red[3];
  sq = red[4] + red[5] + red[6] + red[7];
  const float mu = s * (1.0f / 1024.0f);
  const float var = sq * (1.0f / 1024.0f) - mu * mu;
  const float rstd = rsqrtf(var + 1e-6f);
  float4 g4 = ((const float4*)gam)[t];
  float4 b4 = ((const float4*)bet)[t];
  float4 o;
  o.x = (v.x - mu) * rstd * g4.x + b4.x;
  o.y = (v.y - mu) * rstd * g4.y + b4.y;
  o.z = (v.z - mu) * rstd * g4.z + b4.z;
  o.w = (v.w - mu) * rstd * g4.w + b4.w;
  ((float4*)(out + (size_t)row * 1024))[t] = o;
}

extern "C" void kernel_launch(void* const* d_in, const int* in_sizes, int n_in,
                              void* d_out, int out_size, void* d_ws, size_t ws_size,
                              hipStream_t stream) {
  (void)in_sizes; (void)n_in; (void)out_size; (void)ws_size;
  const float* q = (const float*)d_in[0];
  const float* k = (const float*)d_in[1];
  const float* v = (const float*)d_in[2];
  const int* mask = (const int*)d_in[3];
  const float* wq = (const float*)d_in[4];
  const float* wk = (const float*)d_in[5];
  const float* wv = (const float*)d_in[6];
  const float* fc_w = (const float*)d_in[7];
  const float* ln_g = (const float*)d_in[8];
  const float* ln_b = (const float*)d_in[9];
  float* out = (float*)d_out;

  // workspace layout (~84 MB, same footprint as round 1)
  __bf16* QKVBF = (__bf16*)d_ws;                       // 3 * 4194304 bf16 (dead after gemm_qkv)
  __bf16* W3T   = QKVBF + 3ull * 4194304;              // 3 * 1048576 bf16
  __bf16* WFC   = W3T + 3ull * 1048576;                // 1048576 bf16
  __bf16* HEADS = WFC + 1048576;                       // 3 * 4194304 bf16
  __bf16* CONCAT = HEADS + 3ull * 4194304;             // 4194304 bf16
  float* OUT1 = (float*)(CONCAT + 4194304);            // 4194304 f32
  __bf16* VT = QKVBF;                                  // reuse: V^T [B*H][64][1024]

  cvt3<<<dim3(2048, 3), 256, 0, stream>>>(q, k, v, QKVBF);
  cvt_bf16<<<512, 256, 0, stream>>>(fc_w, WFC, 131072);
  wtrans3<<<dim3(16, 16, 3), 256, 0, stream>>>(wq, wk, wv, W3T);

  gemm_qkv<<<dim3(8, 32, 3), 256, 0, stream>>>(QKVBF, W3T, HEADS);
  vtrans<<<dim3(16, 64), 256, 0, stream>>>(HEADS + 2ull * 4194304, VT);
  attn_kernel<<<1024, 256, 0, stream>>>(HEADS, VT, mask, CONCAT);
  gemm_fc<<<dim3(8, 32), 256, 0, stream>>>(CONCAT, WFC, OUT1, q);
  ln_kernel<<<4096, 256, 0, stream>>>(OUT1, ln_g, ln_b, out);
}

// Round 3
// 149.658 us; speedup vs baseline: 1.2440x; 1.0256x over previous
//
#include <hip/hip_runtime.h>
#include <hip/hip_bf16.h>

typedef __bf16 bf16x8 __attribute__((ext_vector_type(8)));
typedef __bf16 bf16x2 __attribute__((ext_vector_type(2)));
typedef float f32x4 __attribute__((ext_vector_type(4)));
typedef unsigned int u32x2 __attribute__((ext_vector_type(2)));

#define MFMA16(a, b, c) __builtin_amdgcn_mfma_f32_16x16x32_bf16(a, b, c, 0, 0, 0)

static constexpr int M_ = 4096;     // B*S rows

__device__ __forceinline__ void gload_lds16(const void* g, void* l) {
  __builtin_amdgcn_global_load_lds((const __attribute__((address_space(1))) void*)g,
                                   (__attribute__((address_space(3))) void*)l, 16, 0, 0);
}

// swizzled LDS u16 index for 64-col bf16 tiles: 8 granules of 16B per 128B row,
// stored granule = logical granule ^ (row & 7)
#define SWZ(rowv, c16) (((rowv) * 64) + (((c16) ^ ((rowv) & 7)) * 8))

// ---------------- f32 -> bf16 convert: q,k,v in one launch ----------------
__global__ __launch_bounds__(256) void cvt3(const float* __restrict__ q,
                                            const float* __restrict__ k,
                                            const float* __restrict__ v,
                                            __bf16* __restrict__ out) {
  const float* src = blockIdx.y == 0 ? q : (blockIdx.y == 1 ? k : v);
  __bf16* dst = out + (size_t)blockIdx.y * 4194304;
  int i = blockIdx.x * 256 + threadIdx.x;
  const float4* p = (const float4*)src + (size_t)i * 2;
  float4 a = p[0], b = p[1];
  bf16x8 o;
  o[0] = (__bf16)a.x; o[1] = (__bf16)a.y; o[2] = (__bf16)a.z; o[3] = (__bf16)a.w;
  o[4] = (__bf16)b.x; o[5] = (__bf16)b.y; o[6] = (__bf16)b.z; o[7] = (__bf16)b.w;
  *((bf16x8*)dst + i) = o;
}

__global__ __launch_bounds__(256) void cvt_bf16(const float* __restrict__ in,
                                                __bf16* __restrict__ out, int n8) {
  int i = blockIdx.x * 256 + threadIdx.x;
  if (i >= n8) return;
  const float4* p = (const float4*)in + (size_t)i * 2;
  float4 a = p[0], b = p[1];
  bf16x8 o;
  o[0] = (__bf16)a.x; o[1] = (__bf16)a.y; o[2] = (__bf16)a.z; o[3] = (__bf16)a.w;
  o[4] = (__bf16)b.x; o[5] = (__bf16)b.y; o[6] = (__bf16)b.z; o[7] = (__bf16)b.w;
  *((bf16x8*)out + i) = o;
}

// ---------------- mask -> ballot bits: [B][S][S] i32 -> [B][16][1024] u64 ----------------
__global__ __launch_bounds__(256) void mask_bits(const int* __restrict__ mask,
                                                 unsigned long long* __restrict__ bits) {
  const int wid = blockIdx.x * 4 + (threadIdx.x >> 6);   // 0..4095
  const int lane = threadIdx.x & 63;
#pragma unroll
  for (int i = 0; i < 16; ++i) {
    int widx = wid * 16 + i;                 // (b*16 + kt)*1024 + qrow
    int qrow = widx & 1023;
    int bkt = widx >> 10;
    int b = bkt >> 4, kt = bkt & 15;
    int mval = mask[((size_t)b * 1024 + qrow) * 1024 + kt * 64 + lane];
    unsigned long long bal = __ballot(mval != 0);
    if (lane == 0) bits[widx] = bal;
  }
}

// ---------------- per-head weight [H][D][64] -> transposed bf16 [H*64][D], x3 ----------------
__global__ __launch_bounds__(256) void wtrans3(const float* __restrict__ wq,
                                               const float* __restrict__ wk,
                                               const float* __restrict__ wv,
                                               __bf16* __restrict__ out) {
  const int z = blockIdx.z;
  const float* w = z == 0 ? wq : (z == 1 ? wk : wv);
  // fold 1/sqrt(DK) AND log2(e) into W_q so softmax runs in exp2 domain
  const float scale = z == 0 ? 0.125f * 1.4426950408889634f : 1.0f;
  __bf16* o = out + (size_t)z * 1048576;
  __shared__ float tile[64][65];
  const int h = blockIdx.x, d0 = blockIdx.y * 64;
  const int t = threadIdx.x;
  const int r = t >> 2, c0 = (t & 3) * 16;
  const float4* s4 = (const float4*)(w + ((size_t)h * 1024 + d0 + r) * 64 + c0);
#pragma unroll
  for (int j = 0; j < 4; ++j) {
    float4 vv = s4[j];
    tile[r][c0 + 4 * j + 0] = vv.x; tile[r][c0 + 4 * j + 1] = vv.y;
    tile[r][c0 + 4 * j + 2] = vv.z; tile[r][c0 + 4 * j + 3] = vv.w;
  }
  __syncthreads();
  __bf16* dst = o + ((size_t)(h * 64 + r)) * 1024 + d0 + c0;
  bf16x8 o0, o1;
#pragma unroll
  for (int j = 0; j < 8; ++j) o0[j] = (__bf16)(tile[c0 + j][r] * scale);
#pragma unroll
  for (int j = 0; j < 8; ++j) o1[j] = (__bf16)(tile[c0 + 8 + j][r] * scale);
  *(bf16x8*)dst = o0;
  *(bf16x8*)(dst + 8) = o1;
}

// ---------------- V transpose: [B*H][1024][64] -> [B*H][64][1024] ----------------
__global__ __launch_bounds__(256) void vtrans(const __bf16* __restrict__ V,
                                              __bf16* __restrict__ VT) {
  __shared__ __bf16 t[64][65];
  const int bh = blockIdx.y;
  const int s0 = blockIdx.x * 64;
  const int tid = threadIdx.x;
  const int r = tid >> 2, c0 = (tid & 3) * 16;
  const __bf16* src = V + ((size_t)bh * 1024 + s0 + r) * 64 + c0;
  bf16x8 a = *(const bf16x8*)src;
  bf16x8 b = *(const bf16x8*)(src + 8);
#pragma unroll
  for (int j = 0; j < 8; ++j) { t[r][c0 + j] = a[j]; t[r][c0 + 8 + j] = b[j]; }
  __syncthreads();
  bf16x8 o0, o1;
#pragma unroll
  for (int j = 0; j < 8; ++j) o0[j] = t[c0 + j][r];
#pragma unroll
  for (int j = 0; j < 8; ++j) o1[j] = t[c0 + 8 + j][r];
  __bf16* dst = VT + ((size_t)bh * 64 + r) * 1024 + s0 + c0;
  *(bf16x8*)dst = o0;
  *(bf16x8*)(dst + 8) = o1;
}

// ---------------- 128x128 bf16 GEMM, B stored [N][K] (m97 structure) ----------------
template <int MODE>
__device__ __forceinline__ void gemm_core(const __bf16* __restrict__ A,
                                          const __bf16* __restrict__ Bt,
                                          __bf16* __restrict__ outb,
                                          float* __restrict__ outf,
                                          const float* __restrict__ resid) {
  __shared__ __bf16 As[128 * 32];
  __shared__ __bf16 Bs[128 * 32];
  const int bn = blockIdx.x, bm = blockIdx.y;
  const int tid = threadIdx.x, lane = tid & 63;
  const int w = tid >> 6;
  const int wr = (w >> 1) * 64, wc = (w & 1) * 64;
  const int lr = lane & 15, lh = lane >> 4;

  f32x4 acc[4][4];
#pragma unroll
  for (int m = 0; m < 4; ++m)
#pragma unroll
    for (int n = 0; n < 4; ++n) {
      f32x4 z = {0.f, 0.f, 0.f, 0.f};
      acc[m][n] = z;
    }

  for (int kt = 0; kt < 1024 / 32; ++kt) {
#pragma unroll
    for (int i = 0; i < 2; ++i) {
      int o = i * 4096 + tid * 16;
      int row = o >> 6, cb = o & 63;
      gload_lds16((const char*)A + (((size_t)(bm * 128 + row)) * 1024 + kt * 32) * 2 + cb,
                  (char*)As + o);
      gload_lds16((const char*)Bt + (((size_t)(bn * 128 + row)) * 1024 + kt * 32) * 2 + cb,
                  (char*)Bs + o);
    }
    __syncthreads();
    bf16x8 af[4], bfr[4];
#pragma unroll
    for (int m = 0; m < 4; ++m) af[m] = *(const bf16x8*)&As[(wr + m * 16 + lr) * 32 + lh * 8];
#pragma unroll
    for (int n = 0; n < 4; ++n) bfr[n] = *(const bf16x8*)&Bs[(wc + n * 16 + lr) * 32 + lh * 8];
#pragma unroll
    for (int m = 0; m < 4; ++m)
#pragma unroll
      for (int n = 0; n < 4; ++n) acc[m][n] = MFMA16(af[m], bfr[n], acc[m][n]);
    __syncthreads();
  }

  const int r0 = bm * 128 + wr + lh * 4;
  const int c0 = bn * 128 + wc + lr;
#pragma unroll
  for (int m = 0; m < 4; ++m)
#pragma unroll
    for (int n = 0; n < 4; ++n)
#pragma unroll
      for (int reg = 0; reg < 4; ++reg) {
        int row = r0 + m * 16 + reg;
        int col = c0 + n * 16;
        float v = acc[m][n][reg];
        if (MODE == 0) {
          outb[((((size_t)(row >> 10)) * 16 + (col >> 6)) * 1024 + (row & 1023)) * 64 +
               (col & 63)] = (__bf16)v;
        } else {
          size_t idx = (size_t)row * 1024 + col;
          outf[idx] = v + resid[idx];
        }
      }
}

__global__ __launch_bounds__(256) void gemm_qkv(const __bf16* __restrict__ A,
                                                const __bf16* __restrict__ Bt,
                                                __bf16* __restrict__ O) {
  const int z = blockIdx.z;
  gemm_core<0>(A + (size_t)z * 4194304, Bt + (size_t)z * 1048576, O + (size_t)z * 4194304,
               nullptr, nullptr);
}

__global__ __launch_bounds__(256) void gemm_fc(const __bf16* __restrict__ A,
                                               const __bf16* __restrict__ Bt,
                                               float* __restrict__ O,
                                               const float* __restrict__ resid) {
  gemm_core<1>(A, Bt, nullptr, O, resid);
}

// ---------------- flash attention (swapped QK^T: lane owns one q-row) ----------------
__global__ __launch_bounds__(256) void attn_kernel(const __bf16* __restrict__ HEADS,
                                                   const __bf16* __restrict__ VT,
                                                   const unsigned long long* __restrict__ mbits,
                                                   __bf16* __restrict__ concat) {
  const __bf16* QH = HEADS;
  const __bf16* KH = HEADS + (size_t)M_ * 1024;
  __shared__ __bf16 Ks[2][64 * 64];
  __shared__ __bf16 Vs[2][64 * 64];
  __shared__ unsigned int Psw[4][16 * 32];   // per-wave P pair-words, swizzled

  // XCD-aware remap: each XCD gets whole (b,h) groups
  const int d = blockIdx.x;
  const int xcd = d & 7, j = d >> 3;
  const int grp = xcd * 8 + (j >> 4);
  const int qt = j & 15;
  const int h = grp & 15, b = grp >> 4;

  const int tid = threadIdx.x, lane = tid & 63, w = tid >> 6;
  const int lr = lane & 15, lh = lane >> 4;
  const size_t headoff = ((size_t)b * 16 + h) * 65536;
  const char* Kbase = (const char*)(KH + headoff);
  const char* Vbase = (const char*)(VT + headoff);   // [64][1024] per head

  int koff[2], voff[2], ldso[2];
#pragma unroll
  for (int i = 0; i < 2; ++i) {
    int L = i * 256 + tid;
    int row = L >> 3, g = L & 7;
    int gsw = g ^ (row & 7);
    ldso[i] = L * 16;
    koff[i] = row * 128 + gsw * 16;
    voff[i] = row * 2048 + gsw * 16;
  }

  const int qrow = qt * 64 + w * 16 + lr;    // this lane's q-row
  bf16x8 qa[2];
  {
    const __bf16* qptr = QH + headoff + (size_t)qrow * 64 + lh * 8;
    qa[0] = *(const bf16x8*)qptr;
    qa[1] = *(const bf16x8*)(qptr + 32);
  }
  f32x4 oacc[4];
#pragma unroll
  for (int g = 0; g < 4; ++g) {
    f32x4 z = {0.f, 0.f, 0.f, 0.f};
    oacc[g] = z;
  }
  float mrun = -3.0e38f, lrun = 0.f;         // per-lane (q = lr), dup across lh

  const unsigned long long* mbase = mbits + (size_t)b * 16384 + qrow;

  // prologue: stage tile 0
#pragma unroll
  for (int i = 0; i < 2; ++i) {
    gload_lds16(Kbase + koff[i], (char*)Ks[0] + ldso[i]);
    gload_lds16(Vbase + voff[i], (char*)Vs[0] + ldso[i]);
  }
  __syncthreads();

  for (int kt = 0; kt < 16; ++kt) {
    const int cur = kt & 1;
    if (kt < 15) {
#pragma unroll
      for (int i = 0; i < 2; ++i) {
        gload_lds16(Kbase + (size_t)(kt + 1) * 8192 + koff[i], (char*)Ks[cur ^ 1] + ldso[i]);
        gload_lds16(Vbase + (size_t)(kt + 1) * 128 + voff[i], (char*)Vs[cur ^ 1] + ldso[i]);
      }
    }
    const unsigned long long mw = mbase[kt * 1024];  // one u64: 64 kk-bits of this q-row

    // S^T = K Q^T : C row = kk_local (n*16 + lh*4 + r), col = q (lr)
    f32x4 s[4];
#pragma unroll
    for (int n = 0; n < 4; ++n) {
      f32x4 z = {0.f, 0.f, 0.f, 0.f};
      s[n] = z;
    }
    __builtin_amdgcn_s_setprio(1);
#pragma unroll
    for (int n = 0; n < 4; ++n)
#pragma unroll
      for (int h2 = 0; h2 < 2; ++h2) {
        bf16x8 kb = *(const bf16x8*)&Ks[cur][SWZ(n * 16 + lr, h2 * 4 + lh)];
        s[n] = MFMA16(kb, qa[h2], s[n]);
      }
    __builtin_amdgcn_s_setprio(0);

    // mask via bit test (bit index = kk_local)
    const unsigned mlo = (unsigned)mw, mhi = (unsigned)(mw >> 32);
#pragma unroll
    for (int n = 0; n < 4; ++n) {
      unsigned mword = (n & 2) ? mhi : mlo;
      int base = (n & 1) * 16 + lh * 4;
#pragma unroll
      for (int r = 0; r < 4; ++r) {
        unsigned bit = (mword >> (base + r)) & 1u;
        s[n][r] = bit ? s[n][r] : -1.5e9f;
      }
    }

    // online softmax, in-lane (exp2 domain; log2e folded into W_q)
    float pmax = -3.0e38f;
#pragma unroll
    for (int n = 0; n < 4; ++n)
#pragma unroll
      for (int r = 0; r < 4; ++r) pmax = fmaxf(pmax, s[n][r]);
    pmax = fmaxf(pmax, __shfl_xor(pmax, 16, 64));
    pmax = fmaxf(pmax, __shfl_xor(pmax, 32, 64));
    const float mnew = fmaxf(mrun, pmax);
    const float al = exp2f(mrun - mnew);
    mrun = mnew;
    float rsum = 0.f;
#pragma unroll
    for (int n = 0; n < 4; ++n)
#pragma unroll
      for (int r = 0; r < 4; ++r) {
        float p = exp2f(s[n][r] - mrun);
        s[n][r] = p;
        rsum += p;
      }
    rsum += __shfl_xor(rsum, 16, 64);
    rsum += __shfl_xor(rsum, 32, 64);
    lrun = lrun * al + rsum;

    // broadcast al to this lane's oacc rows (q' = lh*4 + r lives at lane lr = q')
    float al4[4];
#pragma unroll
    for (int r = 0; r < 4; ++r) al4[r] = __shfl(al, (lane & 48) | (lh * 4 + r), 64);
#pragma unroll
    for (int g = 0; g < 4; ++g)
#pragma unroll
      for (int r = 0; r < 4; ++r) oacc[g][r] *= al4[r];

    // pack P pairs -> LDS (swizzled), wave-local; pw = kk>>1 = n*8 + lh*2 + u
#pragma unroll
    for (int n = 0; n < 4; ++n) {
      bf16x2 p0, p1;
      p0[0] = (__bf16)s[n][0]; p0[1] = (__bf16)s[n][1];
      p1[0] = (__bf16)s[n][2]; p1[1] = (__bf16)s[n][3];
      int pw0 = n * 8 + lh * 2;
      int addr = lr * 32 + (((pw0 >> 2) ^ (lr & 7)) << 2) + (pw0 & 3);
      u32x2 wv;
      wv[0] = __builtin_bit_cast(unsigned int, p0);
      wv[1] = __builtin_bit_cast(unsigned int, p1);
      *(u32x2*)&Psw[w][addr] = wv;
    }
    bf16x8 pa[2];
#pragma unroll
    for (int h2 = 0; h2 < 2; ++h2) {
      int gr = h2 * 4 + lh;
      pa[h2] = *(const bf16x8*)&Psw[w][lr * 32 + ((gr ^ (lr & 7)) << 2)];
    }

    // O += P V
    __builtin_amdgcn_s_setprio(1);
#pragma unroll
    for (int g = 0; g < 4; ++g)
#pragma unroll
      for (int h2 = 0; h2 < 2; ++h2) {
        bf16x8 vb = *(const bf16x8*)&Vs[cur][SWZ(g * 16 + lr, h2 * 4 + lh)];
        oacc[g] = MFMA16(pa[h2], vb, oacc[g]);
      }
    __builtin_amdgcn_s_setprio(0);
    __syncthreads();
  }

  // epilogue: normalize by l (fetch per-row values) and store
  const float invl = 1.0f / lrun;
  float inv4[4];
#pragma unroll
  for (int r = 0; r < 4; ++r) inv4[r] = __shfl(invl, (lane & 48) | (lh * 4 + r), 64);
  const int qg0 = qt * 64 + w * 16 + lh * 4;
#pragma unroll
  for (int r = 0; r < 4; ++r)
#pragma unroll
    for (int g = 0; g < 4; ++g)
      concat[((size_t)b * 1024 + qg0 + r) * 1024 + h * 64 + g * 16 + lr] =
          (__bf16)(oacc[g][r] * inv4[r]);
}

// ---------------- LayerNorm ----------------
__global__ __launch_bounds__(256) void ln_kernel(const float* __restrict__ in,
                                                 const float* __restrict__ gam,
                                                 const float* __restrict__ bet,
                                                 float* __restrict__ out) {
  const int row = blockIdx.x, t = threadIdx.x;
  const float4* x4 = (const float4*)(in + (size_t)row * 1024);
  float4 v = x4[t];
  float s = v.x + v.y + v.z + v.w;
  float sq = v.x * v.x + v.y * v.y + v.z * v.z + v.w * v.w;
#pragma unroll
  for (int off = 1; off < 64; off <<= 1) {
    s += __shfl_xor(s, off, 64);
    sq += __shfl_xor(sq, off, 64);
  }
  __shared__ float red[8];
  const int w = t >> 6, lane = t & 63;
  if (lane == 0) { red[w] = s; red[4 + w] = sq; }
  __syncthreads();
  s = red[0] + red[1] + red[2] + red[3];
  sq = red[4] + red[5] + red[6] + red[7];
  const float mu = s * (1.0f / 1024.0f);
  const float var = sq * (1.0f / 1024.0f) - mu * mu;
  const float rstd = rsqrtf(var + 1e-6f);
  float4 g4 = ((const float4*)gam)[t];
  float4 b4 = ((const float4*)bet)[t];
  float4 o;
  o.x = (v.x - mu) * rstd * g4.x + b4.x;
  o.y = (v.y - mu) * rstd * g4.y + b4.y;
  o.z = (v.z - mu) * rstd * g4.z + b4.z;
  o.w = (v.w - mu) * rstd * g4.w + b4.w;
  ((float4*)(out + (size_t)row * 1024))[t] = o;
}

extern "C" void kernel_launch(void* const* d_in, const int* in_sizes, int n_in,
                              void* d_out, int out_size, void* d_ws, size_t ws_size,
                              hipStream_t stream) {
  (void)in_sizes; (void)n_in; (void)out_size; (void)ws_size;
  const float* q = (const float*)d_in[0];
  const float* k = (const float*)d_in[1];
  const float* v = (const float*)d_in[2];
  const int* mask = (const int*)d_in[3];
  const float* wq = (const float*)d_in[4];
  const float* wk = (const float*)d_in[5];
  const float* wv = (const float*)d_in[6];
  const float* fc_w = (const float*)d_in[7];
  const float* ln_g = (const float*)d_in[8];
  const float* ln_b = (const float*)d_in[9];
  float* out = (float*)d_out;

  // workspace layout (~80 MB)
  __bf16* QKVBF = (__bf16*)d_ws;                       // 3 * 4194304 bf16 (dead after gemm_qkv)
  __bf16* W3T   = QKVBF + 3ull * 4194304;              // 3 * 1048576 bf16
  __bf16* WFC   = W3T + 3ull * 1048576;                // 1048576 bf16
  __bf16* HEADS = WFC + 1048576;                       // 3 * 4194304 bf16
  __bf16* CONCAT = HEADS + 3ull * 4194304;             // 4194304 bf16
  float* OUT1 = (float*)(CONCAT + 4194304);            // 4194304 f32
  __bf16* VT = QKVBF;                                  // reuse: V^T [B*H][64][1024]
  // mask bits alias OUT1 (attn reads them BEFORE gemm_fc overwrites OUT1)
  unsigned long long* MASKB = (unsigned long long*)OUT1;   // 65536 u64 = 512 KB

  cvt3<<<dim3(2048, 3), 256, 0, stream>>>(q, k, v, QKVBF);
  cvt_bf16<<<512, 256, 0, stream>>>(fc_w, WFC, 131072);
  wtrans3<<<dim3(16, 16, 3), 256, 0, stream>>>(wq, wk, wv, W3T);
  mask_bits<<<1024, 256, 0, stream>>>(mask, MASKB);

  gemm_qkv<<<dim3(8, 32, 3), 256, 0, stream>>>(QKVBF, W3T, HEADS);
  vtrans<<<dim3(16, 64), 256, 0, stream>>>(HEADS + 2ull * 4194304, VT);
  attn_kernel<<<1024, 256, 0, stream>>>(HEADS, VT, MASKB, CONCAT);
  gemm_fc<<<dim3(8, 32), 256, 0, stream>>>(CONCAT, WFC, OUT1, q);
  ln_kernel<<<4096, 256, 0, stream>>>(OUT1, ln_g, ln_b, out);
}

// Round 4
// 144.983 us; speedup vs baseline: 1.2841x; 1.0322x over previous
//
#include <hip/hip_runtime.h>
#include <hip/hip_bf16.h>

typedef __bf16 bf16x8 __attribute__((ext_vector_type(8)));
typedef __bf16 bf16x2 __attribute__((ext_vector_type(2)));
typedef float f32x4 __attribute__((ext_vector_type(4)));
typedef unsigned int u32x2 __attribute__((ext_vector_type(2)));

#define MFMA16(a, b, c) __builtin_amdgcn_mfma_f32_16x16x32_bf16(a, b, c, 0, 0, 0)

static constexpr int M_ = 4096;     // B*S rows

__device__ __forceinline__ void gload_lds16(const void* g, void* l) {
  __builtin_amdgcn_global_load_lds((const __attribute__((address_space(1))) void*)g,
                                   (__attribute__((address_space(3))) void*)l, 16, 0, 0);
}

// swizzled LDS u16 index for 64-col bf16 tiles: 8 granules of 16B per 128B row,
// stored granule = logical granule ^ (row & 7)
#define SWZ(rowv, c16) (((rowv) * 64) + (((c16) ^ ((rowv) & 7)) * 8))

// ---------------- f32 -> bf16 convert: q,k,v in one launch ----------------
__global__ __launch_bounds__(256) void cvt3(const float* __restrict__ q,
                                            const float* __restrict__ k,
                                            const float* __restrict__ v,
                                            __bf16* __restrict__ out) {
  const float* src = blockIdx.y == 0 ? q : (blockIdx.y == 1 ? k : v);
  __bf16* dst = out + (size_t)blockIdx.y * 4194304;
  int i = blockIdx.x * 256 + threadIdx.x;
  const float4* p = (const float4*)src + (size_t)i * 2;
  float4 a = p[0], b = p[1];
  bf16x8 o;
  o[0] = (__bf16)a.x; o[1] = (__bf16)a.y; o[2] = (__bf16)a.z; o[3] = (__bf16)a.w;
  o[4] = (__bf16)b.x; o[5] = (__bf16)b.y; o[6] = (__bf16)b.z; o[7] = (__bf16)b.w;
  *((bf16x8*)dst + i) = o;
}

__global__ __launch_bounds__(256) void cvt_bf16(const float* __restrict__ in,
                                                __bf16* __restrict__ out, int n8) {
  int i = blockIdx.x * 256 + threadIdx.x;
  if (i >= n8) return;
  const float4* p = (const float4*)in + (size_t)i * 2;
  float4 a = p[0], b = p[1];
  bf16x8 o;
  o[0] = (__bf16)a.x; o[1] = (__bf16)a.y; o[2] = (__bf16)a.z; o[3] = (__bf16)a.w;
  o[4] = (__bf16)b.x; o[5] = (__bf16)b.y; o[6] = (__bf16)b.z; o[7] = (__bf16)b.w;
  *((bf16x8*)out + i) = o;
}

// ---------------- mask -> ballot bits: [B][S][S] i32 -> [B][16][1024] u64 ----------------
__global__ __launch_bounds__(256) void mask_bits(const int* __restrict__ mask,
                                                 unsigned long long* __restrict__ bits) {
  const int wid = blockIdx.x * 4 + (threadIdx.x >> 6);   // 0..4095
  const int lane = threadIdx.x & 63;
#pragma unroll
  for (int i = 0; i < 16; ++i) {
    int widx = wid * 16 + i;                 // (b*16 + kt)*1024 + qrow
    int qrow = widx & 1023;
    int bkt = widx >> 10;
    int b = bkt >> 4, kt = bkt & 15;
    int mval = mask[((size_t)b * 1024 + qrow) * 1024 + kt * 64 + lane];
    unsigned long long bal = __ballot(mval != 0);
    if (lane == 0) bits[widx] = bal;
  }
}

// ---------------- per-head weight [H][D][64] -> transposed bf16 [H*64][D], x3 ----------------
__global__ __launch_bounds__(256) void wtrans3(const float* __restrict__ wq,
                                               const float* __restrict__ wk,
                                               const float* __restrict__ wv,
                                               __bf16* __restrict__ out) {
  const int z = blockIdx.z;
  const float* w = z == 0 ? wq : (z == 1 ? wk : wv);
  // fold 1/sqrt(DK) AND log2(e) into W_q so softmax runs in exp2 domain
  const float scale = z == 0 ? 0.125f * 1.4426950408889634f : 1.0f;
  __bf16* o = out + (size_t)z * 1048576;
  __shared__ float tile[64][65];
  const int h = blockIdx.x, d0 = blockIdx.y * 64;
  const int t = threadIdx.x;
  const int r = t >> 2, c0 = (t & 3) * 16;
  const float4* s4 = (const float4*)(w + ((size_t)h * 1024 + d0 + r) * 64 + c0);
#pragma unroll
  for (int j = 0; j < 4; ++j) {
    float4 vv = s4[j];
    tile[r][c0 + 4 * j + 0] = vv.x; tile[r][c0 + 4 * j + 1] = vv.y;
    tile[r][c0 + 4 * j + 2] = vv.z; tile[r][c0 + 4 * j + 3] = vv.w;
  }
  __syncthreads();
  __bf16* dst = o + ((size_t)(h * 64 + r)) * 1024 + d0 + c0;
  bf16x8 o0, o1;
#pragma unroll
  for (int j = 0; j < 8; ++j) o0[j] = (__bf16)(tile[c0 + j][r] * scale);
#pragma unroll
  for (int j = 0; j < 8; ++j) o1[j] = (__bf16)(tile[c0 + 8 + j][r] * scale);
  *(bf16x8*)dst = o0;
  *(bf16x8*)(dst + 8) = o1;
}

// ---------------- QKV GEMM 128x128 (z==2 writes V^T layout directly) ----------------
__global__ __launch_bounds__(256) void gemm_qkv(const __bf16* __restrict__ Abase,
                                                const __bf16* __restrict__ Btbase,
                                                __bf16* __restrict__ HEADS) {
  __shared__ __bf16 As[128 * 32];
  __shared__ __bf16 Bs[128 * 32];
  const int z = blockIdx.z;
  const __bf16* A = Abase + (size_t)z * 4194304;
  const __bf16* Bt = Btbase + (size_t)z * 1048576;
  const int bn = blockIdx.x, bm = blockIdx.y;
  const int tid = threadIdx.x, lane = tid & 63;
  const int w = tid >> 6;
  const int wr = (w >> 1) * 64, wc = (w & 1) * 64;
  const int lr = lane & 15, lh = lane >> 4;

  f32x4 acc[4][4];
#pragma unroll
  for (int m = 0; m < 4; ++m)
#pragma unroll
    for (int n = 0; n < 4; ++n) {
      f32x4 zz = {0.f, 0.f, 0.f, 0.f};
      acc[m][n] = zz;
    }

  for (int kt = 0; kt < 32; ++kt) {
#pragma unroll
    for (int i = 0; i < 2; ++i) {
      int o = i * 4096 + tid * 16;
      int row = o >> 6, cb = o & 63;
      gload_lds16((const char*)A + (((size_t)(bm * 128 + row)) * 1024 + kt * 32) * 2 + cb,
                  (char*)As + o);
      gload_lds16((const char*)Bt + (((size_t)(bn * 128 + row)) * 1024 + kt * 32) * 2 + cb,
                  (char*)Bs + o);
    }
    __syncthreads();
    bf16x8 af[4], bfr[4];
#pragma unroll
    for (int m = 0; m < 4; ++m) af[m] = *(const bf16x8*)&As[(wr + m * 16 + lr) * 32 + lh * 8];
#pragma unroll
    for (int n = 0; n < 4; ++n) bfr[n] = *(const bf16x8*)&Bs[(wc + n * 16 + lr) * 32 + lh * 8];
#pragma unroll
    for (int m = 0; m < 4; ++m)
#pragma unroll
      for (int n = 0; n < 4; ++n) acc[m][n] = MFMA16(af[m], bfr[n], acc[m][n]);
    __syncthreads();
  }

  const int r0 = bm * 128 + wr + lh * 4;
  const int c0 = bn * 128 + wc + lr;
#pragma unroll
  for (int m = 0; m < 4; ++m)
#pragma unroll
    for (int n = 0; n < 4; ++n)
#pragma unroll
      for (int reg = 0; reg < 4; ++reg) {
        int row = r0 + m * 16 + reg;
        int col = c0 + n * 16;
        float v = acc[m][n][reg];
        size_t bh = (size_t)(row >> 10) * 16 + (col >> 6);
        if (z == 2) {
          // V^T: [bh][dk][s]
          HEADS[2ull * 4194304 + (bh * 64 + (col & 63)) * 1024 + (row & 1023)] = (__bf16)v;
        } else {
          HEADS[(size_t)z * 4194304 + (bh * 1024 + (row & 1023)) * 64 + (col & 63)] = (__bf16)v;
        }
      }
}

// ---------------- fc GEMM 64x128 tile (512 blocks -> 2/CU) ----------------
__global__ __launch_bounds__(256) void gemm_fc64(const __bf16* __restrict__ A,
                                                 const __bf16* __restrict__ Bt,
                                                 float* __restrict__ O,
                                                 const float* __restrict__ resid) {
  __shared__ __bf16 As[64 * 32];
  __shared__ __bf16 Bs[128 * 32];
  const int bn = blockIdx.x, bm = blockIdx.y;
  const int tid = threadIdx.x, lane = tid & 63;
  const int w = tid >> 6;
  const int wc = w * 32;
  const int lr = lane & 15, lh = lane >> 4;

  f32x4 acc[4][2];
#pragma unroll
  for (int m = 0; m < 4; ++m)
#pragma unroll
    for (int n = 0; n < 2; ++n) {
      f32x4 z = {0.f, 0.f, 0.f, 0.f};
      acc[m][n] = z;
    }

  for (int kt = 0; kt < 32; ++kt) {
    {
      int o = tid * 16;
      int row = o >> 6, cb = o & 63;
      gload_lds16((const char*)A + (((size_t)(bm * 64 + row)) * 1024 + kt * 32) * 2 + cb,
                  (char*)As + o);
    }
#pragma unroll
    for (int i = 0; i < 2; ++i) {
      int o = i * 4096 + tid * 16;
      int row = o >> 6, cb = o & 63;
      gload_lds16((const char*)Bt + (((size_t)(bn * 128 + row)) * 1024 + kt * 32) * 2 + cb,
                  (char*)Bs + o);
    }
    __syncthreads();
    bf16x8 af[4], bfr[2];
#pragma unroll
    for (int m = 0; m < 4; ++m) af[m] = *(const bf16x8*)&As[(m * 16 + lr) * 32 + lh * 8];
#pragma unroll
    for (int n = 0; n < 2; ++n) bfr[n] = *(const bf16x8*)&Bs[(wc + n * 16 + lr) * 32 + lh * 8];
#pragma unroll
    for (int m = 0; m < 4; ++m)
#pragma unroll
      for (int n = 0; n < 2; ++n) acc[m][n] = MFMA16(af[m], bfr[n], acc[m][n]);
    __syncthreads();
  }

#pragma unroll
  for (int m = 0; m < 4; ++m)
#pragma unroll
    for (int n = 0; n < 2; ++n)
#pragma unroll
      for (int reg = 0; reg < 4; ++reg) {
        int row = bm * 64 + m * 16 + lh * 4 + reg;
        int col = bn * 128 + wc + n * 16 + lr;
        size_t idx = (size_t)row * 1024 + col;
        O[idx] = acc[m][n][reg] + resid[idx];
      }
}

// ---------------- flash attention: 2 q-chains per wave ----------------
__global__ __launch_bounds__(256) void attn_kernel(const __bf16* __restrict__ HEADS,
                                                   const unsigned long long* __restrict__ mbits,
                                                   __bf16* __restrict__ concat) {
  const __bf16* QH = HEADS;
  const __bf16* KH = HEADS + (size_t)M_ * 1024;
  const __bf16* VT = HEADS + (size_t)2 * M_ * 1024;   // [bh][64][1024]
  __shared__ __bf16 Ks[2][64 * 64];
  __shared__ __bf16 Vs[2][64 * 64];
  __shared__ unsigned int Psw[2][4][16 * 32];   // [chain][wave]

  // XCD-aware remap: 8 (b,h) groups per xcd, 8 q-blocks each
  const int d = blockIdx.x;            // 0..511
  const int xcd = d & 7, j = d >> 3;
  const int grp = xcd * 8 + (j >> 3);
  const int qblk = j & 7;              // 128 q-rows
  const int h = grp & 15, b = grp >> 4;

  const int tid = threadIdx.x, lane = tid & 63, w = tid >> 6;
  const int lr = lane & 15, lh = lane >> 4;
  const size_t headoff = ((size_t)b * 16 + h) * 65536;
  const char* Kbase = (const char*)(KH + headoff);
  const char* Vbase = (const char*)(VT + headoff);

  int koff[2], voff[2], ldso[2];
#pragma unroll
  for (int i = 0; i < 2; ++i) {
    int L = i * 256 + tid;
    int row = L >> 3, g = L & 7;
    int gsw = g ^ (row & 7);
    ldso[i] = L * 16;
    koff[i] = row * 128 + gsw * 16;
    voff[i] = row * 2048 + gsw * 16;
  }

  const int qr0 = qblk * 128 + w * 16 + lr;   // chain0 lane q-row
  bf16x8 qa0[2], qa1[2];
  {
    const __bf16* qp0 = QH + headoff + (size_t)qr0 * 64 + lh * 8;
    qa0[0] = *(const bf16x8*)qp0;
    qa0[1] = *(const bf16x8*)(qp0 + 32);
    const __bf16* qp1 = qp0 + 64 * 64;        // +64 q-rows
    qa1[0] = *(const bf16x8*)qp1;
    qa1[1] = *(const bf16x8*)(qp1 + 32);
  }
  f32x4 oacc0[4], oacc1[4];
#pragma unroll
  for (int g = 0; g < 4; ++g) {
    f32x4 z = {0.f, 0.f, 0.f, 0.f};
    oacc0[g] = z; oacc1[g] = z;
  }
  float mrun0 = -3.0e38f, lrun0 = 0.f, mrun1 = -3.0e38f, lrun1 = 0.f;

  const unsigned long long* mb0 = mbits + (size_t)b * 16384 + qr0;
  const unsigned long long* mb1 = mb0 + 64;
  unsigned long long mwA = mb0[0], mwB = mb1[0];

  // prologue: stage tile 0
#pragma unroll
  for (int i = 0; i < 2; ++i) {
    gload_lds16(Kbase + koff[i], (char*)Ks[0] + ldso[i]);
    gload_lds16(Vbase + voff[i], (char*)Vs[0] + ldso[i]);
  }
  __syncthreads();

  for (int kt = 0; kt < 16; ++kt) {
    const int cur = kt & 1;
    unsigned long long mwAn = 0, mwBn = 0;
    if (kt < 15) {
#pragma unroll
      for (int i = 0; i < 2; ++i) {
        gload_lds16(Kbase + (size_t)(kt + 1) * 8192 + koff[i], (char*)Ks[cur ^ 1] + ldso[i]);
        gload_lds16(Vbase + (size_t)(kt + 1) * 128 + voff[i], (char*)Vs[cur ^ 1] + ldso[i]);
      }
      mwAn = mb0[(kt + 1) << 10];
      mwBn = mb1[(kt + 1) << 10];
    }

    // S^T = K Q^T for both chains, sharing K-fragment reads
    f32x4 s0[4], s1[4];
#pragma unroll
    for (int n = 0; n < 4; ++n) {
      f32x4 z = {0.f, 0.f, 0.f, 0.f};
      s0[n] = z; s1[n] = z;
    }
    __builtin_amdgcn_s_setprio(1);
#pragma unroll
    for (int n = 0; n < 4; ++n)
#pragma unroll
      for (int h2 = 0; h2 < 2; ++h2) {
        bf16x8 kb = *(const bf16x8*)&Ks[cur][SWZ(n * 16 + lr, h2 * 4 + lh)];
        s0[n] = MFMA16(kb, qa0[h2], s0[n]);
        s1[n] = MFMA16(kb, qa1[h2], s1[n]);
      }
    __builtin_amdgcn_s_setprio(0);

    // per-chain: mask, online softmax (defer-max), pack P
    bf16x8 pa0[2], pa1[2];
#pragma unroll
    for (int c = 0; c < 2; ++c) {
      f32x4* s = c == 0 ? s0 : s1;
      f32x4* oacc = c == 0 ? oacc0 : oacc1;
      float& mrun = c == 0 ? mrun0 : mrun1;
      float& lrun = c == 0 ? lrun0 : lrun1;
      const unsigned long long mw = c == 0 ? mwA : mwB;

      const unsigned mlo = (unsigned)mw, mhi = (unsigned)(mw >> 32);
#pragma unroll
      for (int n = 0; n < 4; ++n) {
        unsigned mword = (n & 2) ? mhi : mlo;
        int base = (n & 1) * 16 + lh * 4;
#pragma unroll
        for (int r = 0; r < 4; ++r) {
          unsigned bit = (mword >> (base + r)) & 1u;
          s[n][r] = bit ? s[n][r] : -1.5e9f;
        }
      }

      float pmax = -3.0e38f;
#pragma unroll
      for (int n = 0; n < 4; ++n)
#pragma unroll
        for (int r = 0; r < 4; ++r) pmax = fmaxf(pmax, s[n][r]);
      pmax = fmaxf(pmax, __shfl_xor(pmax, 16, 64));
      pmax = fmaxf(pmax, __shfl_xor(pmax, 32, 64));

      // defer-max: only rescale when the running max grew by > 8 (exp2 domain)
      if (!__all(pmax <= mrun + 8.f)) {
        const float mnew = fmaxf(mrun, pmax);
        const float al = exp2f(mrun - mnew);
        mrun = mnew;
        lrun *= al;
        float al4[4];
#pragma unroll
        for (int r = 0; r < 4; ++r) al4[r] = __shfl(al, (lane & 48) | (lh * 4 + r), 64);
#pragma unroll
        for (int g = 0; g < 4; ++g)
#pragma unroll
          for (int r = 0; r < 4; ++r) oacc[g][r] *= al4[r];
      }

      float rsum = 0.f;
#pragma unroll
      for (int n = 0; n < 4; ++n)
#pragma unroll
        for (int r = 0; r < 4; ++r) {
          float p = exp2f(s[n][r] - mrun);
          s[n][r] = p;
          rsum += p;
        }
      rsum += __shfl_xor(rsum, 16, 64);
      rsum += __shfl_xor(rsum, 32, 64);
      lrun += rsum;

      // pack P pairs -> LDS (swizzled)
#pragma unroll
      for (int n = 0; n < 4; ++n) {
        bf16x2 p0, p1;
        p0[0] = (__bf16)s[n][0]; p0[1] = (__bf16)s[n][1];
        p1[0] = (__bf16)s[n][2]; p1[1] = (__bf16)s[n][3];
        int pw0 = n * 8 + lh * 2;
        int addr = lr * 32 + (((pw0 >> 2) ^ (lr & 7)) << 2) + (pw0 & 3);
        u32x2 wv;
        wv[0] = __builtin_bit_cast(unsigned int, p0);
        wv[1] = __builtin_bit_cast(unsigned int, p1);
        *(u32x2*)&Psw[c][w][addr] = wv;
      }
      bf16x8* pa = c == 0 ? pa0 : pa1;
#pragma unroll
      for (int h2 = 0; h2 < 2; ++h2) {
        int gr = h2 * 4 + lh;
        pa[h2] = *(const bf16x8*)&Psw[c][w][lr * 32 + ((gr ^ (lr & 7)) << 2)];
      }
    }

    // O += P V for both chains, sharing V-fragment reads
    __builtin_amdgcn_s_setprio(1);
#pragma unroll
    for (int g = 0; g < 4; ++g)
#pragma unroll
      for (int h2 = 0; h2 < 2; ++h2) {
        bf16x8 vb = *(const bf16x8*)&Vs[cur][SWZ(g * 16 + lr, h2 * 4 + lh)];
        oacc0[g] = MFMA16(pa0[h2], vb, oacc0[g]);
        oacc1[g] = MFMA16(pa1[h2], vb, oacc1[g]);
      }
    __builtin_amdgcn_s_setprio(0);
    mwA = mwAn; mwB = mwBn;
    __syncthreads();
  }

  // epilogue
#pragma unroll
  for (int c = 0; c < 2; ++c) {
    f32x4* oacc = c == 0 ? oacc0 : oacc1;
    const float invl = 1.0f / (c == 0 ? lrun0 : lrun1);
    float inv4[4];
#pragma unroll
    for (int r = 0; r < 4; ++r) inv4[r] = __shfl(invl, (lane & 48) | (lh * 4 + r), 64);
    const int qg0 = qblk * 128 + c * 64 + w * 16 + lh * 4;
#pragma unroll
    for (int r = 0; r < 4; ++r)
#pragma unroll
      for (int g = 0; g < 4; ++g)
        concat[((size_t)b * 1024 + qg0 + r) * 1024 + h * 64 + g * 16 + lr] =
            (__bf16)(oacc[g][r] * inv4[r]);
  }
}

// ---------------- LayerNorm ----------------
__global__ __launch_bounds__(256) void ln_kernel(const float* __restrict__ in,
                                                 const float* __restrict__ gam,
                                                 const float* __restrict__ bet,
                                                 float* __restrict__ out) {
  const int row = blockIdx.x, t = threadIdx.x;
  const float4* x4 = (const float4*)(in + (size_t)row * 1024);
  float4 v = x4[t];
  float s = v.x + v.y + v.z + v.w;
  float sq = v.x * v.x + v.y * v.y + v.z * v.z + v.w * v.w;
#pragma unroll
  for (int off = 1; off < 64; off <<= 1) {
    s += __shfl_xor(s, off, 64);
    sq += __shfl_xor(sq, off, 64);
  }
  __shared__ float red[8];
  const int w = t >> 6, lane = t & 63;
  if (lane == 0) { red[w] = s; red[4 + w] = sq; }
  __syncthreads();
  s = red[0] + red[1] + red[2] + red[3];
  sq = red[4] + red[5] + red[6] + red[7];
  const float mu = s * (1.0f / 1024.0f);
  const float var = sq * (1.0f / 1024.0f) - mu * mu;
  const float rstd = rsqrtf(var + 1e-6f);
  float4 g4 = ((const float4*)gam)[t];
  float4 b4 = ((const float4*)bet)[t];
  float4 o;
  o.x = (v.x - mu) * rstd * g4.x + b4.x;
  o.y = (v.y - mu) * rstd * g4.y + b4.y;
  o.z = (v.z - mu) * rstd * g4.z + b4.z;
  o.w = (v.w - mu) * rstd * g4.w + b4.w;
  ((float4*)(out + (size_t)row * 1024))[t] = o;
}

extern "C" void kernel_launch(void* const* d_in, const int* in_sizes, int n_in,
                              void* d_out, int out_size, void* d_ws, size_t ws_size,
                              hipStream_t stream) {
  (void)in_sizes; (void)n_in; (void)out_size; (void)ws_size;
  const float* q = (const float*)d_in[0];
  const float* k = (const float*)d_in[1];
  const float* v = (const float*)d_in[2];
  const int* mask = (const int*)d_in[3];
  const float* wq = (const float*)d_in[4];
  const float* wk = (const float*)d_in[5];
  const float* wv = (const float*)d_in[6];
  const float* fc_w = (const float*)d_in[7];
  const float* ln_g = (const float*)d_in[8];
  const float* ln_b = (const float*)d_in[9];
  float* out = (float*)d_out;

  // workspace layout (~80 MB)
  __bf16* QKVBF = (__bf16*)d_ws;                       // 3 * 4194304 bf16
  __bf16* W3T   = QKVBF + 3ull * 4194304;              // 3 * 1048576 bf16
  __bf16* WFC   = W3T + 3ull * 1048576;                // 1048576 bf16
  __bf16* HEADS = WFC + 1048576;                       // 3 * 4194304 bf16 (V region = V^T)
  __bf16* CONCAT = HEADS + 3ull * 4194304;             // 4194304 bf16
  float* OUT1 = (float*)(CONCAT + 4194304);            // 4194304 f32
  // mask bits alias OUT1 (attn reads them BEFORE gemm_fc overwrites OUT1)
  unsigned long long* MASKB = (unsigned long long*)OUT1;   // 65536 u64 = 512 KB

  cvt3<<<dim3(2048, 3), 256, 0, stream>>>(q, k, v, QKVBF);
  cvt_bf16<<<512, 256, 0, stream>>>(fc_w, WFC, 131072);
  wtrans3<<<dim3(16, 16, 3), 256, 0, stream>>>(wq, wk, wv, W3T);
  mask_bits<<<1024, 256, 0, stream>>>(mask, MASKB);

  gemm_qkv<<<dim3(8, 32, 3), 256, 0, stream>>>(QKVBF, W3T, HEADS);
  attn_kernel<<<512, 256, 0, stream>>>(HEADS, MASKB, CONCAT);
  gemm_fc64<<<dim3(8, 64), 256, 0, stream>>>(CONCAT, WFC, OUT1, q);
  ln_kernel<<<4096, 256, 0, stream>>>(OUT1, ln_g, ln_b, out);
}